// Round 7
// baseline (726.495 us; speedup 1.0000x reference)
//
#include <hip/hip_runtime.h>

// Correlation, MAX_DISP=4: out[b, dx*9+dy, h, w] =
//   mean_c x1[b,c,h,w] * x2[b,c,h+dx-4,w+dy-4] (x2 zero-padded)
// x1,x2: (8,64,256,256) fp32. out: (8,81,256,256) fp32.
//
// R7: LDS staging via global_load_lds(16B) with pre-swizzled GLOBAL source
// (rule #21: linear LDS dest + inverse-swizzled source + swizzled read),
// 2 channels per barrier phase, double-buffered (4 x 12KB = 48KB LDS).
// Loads for pair p+1 issue right after the barrier, consumed a full
// compute phase later -> vmcnt drain at __syncthreads is ~free.
// OOB x2 row slots zeroed once in prologue, never DMA'd.
// Block = (b, h-pair), 9 waves (wave = dx), lanes 0-31 row h0 / 32-63 h1,
// VW=8. XCD swizzle: b = blockIdx&7.

namespace {
constexpr int kB = 8;
constexpr int kC = 64;
constexpr int kH = 256;
constexpr int kW = 256;
constexpr int kD = 9;              // 2*4+1
constexpr int kRowDw = 256;        // dwords per staged row (1 KB)
constexpr int kRowsPerCh = 12;     // 2 x1 rows + 10 x2 rows
constexpr int kChDw = kRowsPerCh * kRowDw;  // 3072
constexpr int kLdsDw = 4 * kChDw;  // [phase][cc] slots -> 49152 B
constexpr int kThreads = 576;      // 9 waves
}  // namespace

// involution on 16B-block index within a 1KB row; permutes within 128B lines
__device__ __forceinline__ int swz(int b) { return b ^ ((b >> 3) & 7); }

__global__ __launch_bounds__(kThreads) void corr_kernel(
    const float* __restrict__ x1, const float* __restrict__ x2,
    float* __restrict__ out) {
  __shared__ float lds[kLdsDw];

  const int bb = blockIdx.x & 7;   // batch -> XCD under round-robin dispatch
  const int hp = blockIdx.x >> 3;  // 0..127 h-pair
  const int tid = (int)threadIdx.x;
  const int wv = tid >> 6;         // wave = dx (0..8)
  const int lane = tid & 63;
  const int half = lane >> 5;      // 0: row h0, 1: row h1
  const int lh = lane & 31;
  const int h = 2 * hp + half;
  const int w0 = lh * 8;
  const bool hasL = (lh > 0);
  const bool hasR = (lh < 31);
  const float4 z = make_float4(0.f, 0.f, 0.f, 0.f);

  // Zero OOB x2 row slots once (slot->row map is channel-invariant; they
  // are never staged, so they stay zero for all 64 channels).
  if (hp < 2 || hp >= kH / 2 - 2) {
    for (int s = 0; s < 4; ++s)
      for (int r = 2; r < 12; ++r) {
        const int g = 2 * hp + r - 6;
        if (g < 0 || g >= kH)
          for (int i = tid; i < kRowDw; i += kThreads)
            lds[(s * 12 + r) * kRowDw + i] = 0.0f;
      }
  }

  const int swl = swz(lane) * 4;  // pre-swizzled dword offset within a row

  // wave wv stages pair-rows {wv, wv+9, wv+18 if <24}; rp -> (cc, r)
  auto stage = [&](int pair, int ph) {
    const int c0 = 2 * pair;
#pragma unroll
    for (int k = 0; k < 3; ++k) {
      const int rp = wv + 9 * k;
      if (rp >= 24) continue;  // only waves 0..5 have a third row
      const int cc = (rp >= 12) ? 1 : 0;
      const int r = rp - 12 * cc;
      const int ch = c0 + cc;
      const float* src;
      bool valid = true;
      if (r < 2) {  // x1 rows h0,h1
        src = x1 + ((size_t)(bb * kC + ch) * kH + (size_t)(2 * hp + r)) * kW;
      } else {      // x2 row g = 2hp + r - 6
        const int g = 2 * hp + r - 6;
        valid = (g >= 0) && (g < kH);
        src = x2 + ((size_t)(bb * kC + ch) * kH + (size_t)(valid ? g : 0)) * kW;
      }
      if (valid) {
        const float* ga = src + swl;  // per-lane pre-swizzled source
        float* lp = &lds[(ph * 2 + cc) * kChDw + r * kRowDw];  // wave-uniform
        __builtin_amdgcn_global_load_lds(
            (const __attribute__((address_space(1))) float*)ga,
            (__attribute__((address_space(3))) float*)lp, 16, 0, 0);
      }
    }
  };

  // per-lane LDS read offsets (dwords, relative to slot base), swizzled
  const int a0o = half * kRowDw + swz(2 * lh) * 4;
  const int a1o = half * kRowDw + swz(2 * lh + 1) * 4;
  const int rro = (2 + half + wv) * kRowDw;  // x2 row slot for this (half,dx)
  const int t0o = rro + swz((2 * lh - 1) & 63) * 4;
  const int t1o = rro + swz(2 * lh) * 4;
  const int t2o = rro + swz(2 * lh + 1) * 4;
  const int t3o = rro + swz((2 * lh + 2) & 63) * 4;

  float acc[kD][8];
#pragma unroll
  for (int dy = 0; dy < kD; ++dy)
#pragma unroll
    for (int j = 0; j < 8; ++j) acc[dy][j] = 0.0f;

  stage(0, 0);
  __syncthreads();

#pragma unroll 2
  for (int p = 0; p < kC / 2; ++p) {
    const int ph = p & 1;
    if (p + 1 < kC / 2) stage(p + 1, ph ^ 1);  // issue next pair's DMA early

#pragma unroll
    for (int cc = 0; cc < 2; ++cc) {
      const int base = (ph * 2 + cc) * kChDw;
      const float4 A0 = *reinterpret_cast<const float4*>(&lds[base + a0o]);
      const float4 A1 = *reinterpret_cast<const float4*>(&lds[base + a1o]);
      const float4 T0 =
          hasL ? *reinterpret_cast<const float4*>(&lds[base + t0o]) : z;
      const float4 T1 = *reinterpret_cast<const float4*>(&lds[base + t1o]);
      const float4 T2 = *reinterpret_cast<const float4*>(&lds[base + t2o]);
      const float4 T3 =
          hasR ? *reinterpret_cast<const float4*>(&lds[base + t3o]) : z;

      const float av[8] = {A0.x, A0.y, A0.z, A0.w, A1.x, A1.y, A1.z, A1.w};
      const float t[16] = {T0.x, T0.y, T0.z, T0.w, T1.x, T1.y, T1.z, T1.w,
                           T2.x, T2.y, T2.z, T2.w, T3.x, T3.y, T3.z, T3.w};
      // output col w0+j, shift dy: x2 col = w0+j+dy-4 -> t[j+dy] (t[0]=w0-4)
#pragma unroll
      for (int dy = 0; dy < kD; ++dy)
#pragma unroll
        for (int j = 0; j < 8; ++j)
          acc[dy][j] = fmaf(av[j], t[dy + j], acc[dy][j]);
    }
    __syncthreads();
  }

  const float inv = 1.0f / (float)kC;
  float* po = out + (((size_t)bb * (kD * kD) + wv * kD) * kH + h) * kW + w0;
#pragma unroll
  for (int dy = 0; dy < kD; ++dy) {
    const float4 o0 = make_float4(acc[dy][0] * inv, acc[dy][1] * inv,
                                  acc[dy][2] * inv, acc[dy][3] * inv);
    const float4 o1 = make_float4(acc[dy][4] * inv, acc[dy][5] * inv,
                                  acc[dy][6] * inv, acc[dy][7] * inv);
    *reinterpret_cast<float4*>(po) = o0;
    *reinterpret_cast<float4*>(po + 4) = o1;
    po += (size_t)kH * kW;
  }
}

extern "C" void kernel_launch(void* const* d_in, const int* in_sizes, int n_in,
                              void* d_out, int out_size, void* d_ws, size_t ws_size,
                              hipStream_t stream) {
  const float* x1 = (const float*)d_in[0];
  const float* x2 = (const float*)d_in[1];
  float* out = (float*)d_out;
  const int grid = kB * (kH / 2);  // 1024 blocks, 9 waves each
  corr_kernel<<<grid, kThreads, 0, stream>>>(x1, x2, out);
}

// Round 8
// 245.152 us; speedup vs baseline: 2.9634x; 2.9634x over previous
//
#include <hip/hip_runtime.h>

// Correlation, MAX_DISP=4: out[b, dx*9+dy, h, w] =
//   mean_c x1[b,c,h,w] * x2[b,c,h+dx-4,w+dy-4] (x2 zero-padded)
// x1,x2: (8,64,256,256) fp32. out: (8,81,256,256) fp32.
//
// R8: barrier-free L1 sharing. One WG = 9 waves = all 9 dx for one
// (b, h-pair); waves load DIRECTLY from global (R4 per-lane shape:
// lanes 0-31 row h0, 32-63 row h1, VW=8, x2 window w0-4..w0+11 = 4
// float4, x1 = 2 float4). The 9 co-resident waves touch the same 12
// rows (12 KB < 32 KB L1) per channel: first toucher misses to L2,
// rest hit L1 -> L2 traffic ~6x down; L1-return becomes the pipe.
// No LDS, no per-channel barriers (one __syncthreads every 8 channels
// bounds inter-wave drift so the channel working set stays L1-hot).
// XCD swizzle: b = blockIdx&7 (one batch per XCD).

namespace {
constexpr int kB = 8;
constexpr int kC = 64;
constexpr int kH = 256;
constexpr int kW = 256;
constexpr int kD = 9;          // 2*4+1
constexpr int kMD = 4;
constexpr int kCS = kH * kW;   // channel stride
}  // namespace

__global__ __launch_bounds__(576) void corr_kernel(
    const float* __restrict__ x1, const float* __restrict__ x2,
    float* __restrict__ out) {
  const int bb = blockIdx.x & 7;   // batch -> XCD under round-robin dispatch
  const int hp = blockIdx.x >> 3;  // 0..127 h-pair
  const int tid  = (int)threadIdx.x;
  const int wv   = tid >> 6;       // wave = dx (0..8)
  const int lane = tid & 63;
  const int half = lane >> 5;      // 0: row h0, 1: row h1
  const int lh   = lane & 31;
  const int h    = 2 * hp + half;
  const int row  = h + wv - kMD;   // x2 source row (may be OOB)
  const int w0   = lh * 8;

  const bool rowok = (row >= 0) && (row < kH);
  const bool hasL  = rowok && (lh > 0);
  const bool hasR  = rowok && (lh < 31);

  float acc[kD][8];
#pragma unroll
  for (int dy = 0; dy < kD; ++dy)
#pragma unroll
    for (int j = 0; j < 8; ++j) acc[dy][j] = 0.0f;

  const float* p1 = x1 + ((size_t)(bb * kC) * kH + h) * kW + w0;
  const float* p2 = x2 + ((size_t)(bb * kC) * kH + row) * kW + w0;
  const float4 z = make_float4(0.f, 0.f, 0.f, 0.f);

  float4 a0, a1, t0, t1, t2, t3;
  // prologue: channel 0
  a0 = *reinterpret_cast<const float4*>(p1);
  a1 = *reinterpret_cast<const float4*>(p1 + 4);
  t0 = hasL  ? *reinterpret_cast<const float4*>(p2 - 4) : z;
  t1 = rowok ? *reinterpret_cast<const float4*>(p2)     : z;
  t2 = rowok ? *reinterpret_cast<const float4*>(p2 + 4) : z;
  t3 = hasR  ? *reinterpret_cast<const float4*>(p2 + 8) : z;

#pragma unroll 2
  for (int c = 0; c < kC - 1; ++c) {
    p1 += kCS;
    p2 += kCS;
    // prefetch next channel
    float4 na0 = *reinterpret_cast<const float4*>(p1);
    float4 na1 = *reinterpret_cast<const float4*>(p1 + 4);
    float4 nt0 = hasL  ? *reinterpret_cast<const float4*>(p2 - 4) : z;
    float4 nt1 = rowok ? *reinterpret_cast<const float4*>(p2)     : z;
    float4 nt2 = rowok ? *reinterpret_cast<const float4*>(p2 + 4) : z;
    float4 nt3 = hasR  ? *reinterpret_cast<const float4*>(p2 + 8) : z;

    {
      const float av[8] = {a0.x, a0.y, a0.z, a0.w, a1.x, a1.y, a1.z, a1.w};
      const float t[16] = {t0.x, t0.y, t0.z, t0.w, t1.x, t1.y, t1.z, t1.w,
                           t2.x, t2.y, t2.z, t2.w, t3.x, t3.y, t3.z, t3.w};
      // output col w0+j, shift dy: x2 col = w0+j+dy-4 -> t[j+dy] (t[0]=w0-4)
#pragma unroll
      for (int dy = 0; dy < kD; ++dy)
#pragma unroll
        for (int j = 0; j < 8; ++j)
          acc[dy][j] = fmaf(av[j], t[dy + j], acc[dy][j]);
    }

    a0 = na0; a1 = na1; t0 = nt0; t1 = nt1; t2 = nt2; t3 = nt3;

    // bound inter-wave drift so the WG's 12-row working set stays L1-hot
    if ((c & 7) == 6) __syncthreads();
  }
  {  // epilogue: last channel
    const float av[8] = {a0.x, a0.y, a0.z, a0.w, a1.x, a1.y, a1.z, a1.w};
    const float t[16] = {t0.x, t0.y, t0.z, t0.w, t1.x, t1.y, t1.z, t1.w,
                         t2.x, t2.y, t2.z, t2.w, t3.x, t3.y, t3.z, t3.w};
#pragma unroll
    for (int dy = 0; dy < kD; ++dy)
#pragma unroll
      for (int j = 0; j < 8; ++j)
        acc[dy][j] = fmaf(av[j], t[dy + j], acc[dy][j]);
  }

  const float inv = 1.0f / (float)kC;
  float* po = out + (((size_t)bb * (kD * kD) + wv * kD) * kH + h) * kW + w0;
#pragma unroll
  for (int dy = 0; dy < kD; ++dy) {
    const float4 o0 = make_float4(acc[dy][0] * inv, acc[dy][1] * inv,
                                  acc[dy][2] * inv, acc[dy][3] * inv);
    const float4 o1 = make_float4(acc[dy][4] * inv, acc[dy][5] * inv,
                                  acc[dy][6] * inv, acc[dy][7] * inv);
    *reinterpret_cast<float4*>(po)     = o0;
    *reinterpret_cast<float4*>(po + 4) = o1;
    po += (size_t)kH * kW;
  }
}

extern "C" void kernel_launch(void* const* d_in, const int* in_sizes, int n_in,
                              void* d_out, int out_size, void* d_ws, size_t ws_size,
                              hipStream_t stream) {
  const float* x1 = (const float*)d_in[0];
  const float* x2 = (const float*)d_in[1];
  float* out = (float*)d_out;
  const int grid = kB * (kH / 2);  // 1024 blocks, 9 waves each
  corr_kernel<<<grid, 576, 0, stream>>>(x1, x2, out);
}